// Round 3
// baseline (39.570 us; speedup 1.0000x reference)
//
#include <hip/hip_runtime.h>
#include <hip/hip_bf16.h>
#include <math.h>

// Problem constants (from reference setup_inputs)
constexpr int B_  = 192;
constexpr int NY  = 48;
constexpr int NT  = 48;
constexpr int C_  = 6625;
constexpr int EPB = NT * NY;          // 2304 elements per (b, array)

// DPP move helper (compile-time ctrl). Invalid/masked lanes get `identity`.
template<int CTRL, int RM>
__device__ __forceinline__ float dpp_movf(float identity, float x) {
    int r = __builtin_amdgcn_update_dpp(__builtin_bit_cast(int, identity),
                                        __builtin_bit_cast(int, x),
                                        CTRL, RM, 0xf, false);
    return __builtin_bit_cast(float, r);
}
// ctrl: ROW_SHR|n = 0x110|n, WAVE_SHR1 = 0x138, ROW_BCAST15 = 0x142, ROW_BCAST31 = 0x143

// ---------- Kernel A: flat gather across all CUs ----------
// One thread per (b, t, j); loads pred & I at the same scattered offset,
// writes compacted [b][t][j] arrays into ws. Maximizes chip-wide outstanding
// misses: 1728 blocks spread over all 256 CUs, ~32 waves/CU.
__global__ __launch_bounds__(256) void ep_gather_kernel(
    const float* __restrict__ pred,
    const float* __restrict__ I,
    const int*   __restrict__ tgt,
    float* __restrict__ wsP,
    float* __restrict__ wsI,
    int*   __restrict__ cnt)
{
    int e = blockIdx.x * 256 + threadIdx.x;      // [0, 442368)
    if (e == 0) *cnt = 0;                        // init counter for kernel B
    int b = e / EPB;
    int i = e - b * EPB;
    int t = i / NY;
    int j = i - t * NY;
    int c = tgt[b * NT + t];
    size_t off = (size_t)b * (NY * C_) + (size_t)j * C_ + (size_t)c;
    float pv = __builtin_nontemporal_load(pred + off);
    float iv = __builtin_nontemporal_load(I + off);
    wsP[e] = fmaxf(pv, 0.0f);
    wsI[e] = fmaxf(iv, 0.0f);
}

// ---------- Kernel B: 4 scans per block (1 per wave) + fused reduction ----------
__global__ __launch_bounds__(256) void ep_scan_kernel(
    const float* __restrict__ R,
    const int*   __restrict__ tgt,
    const float* __restrict__ wsP,
    const float* __restrict__ wsI,
    float* __restrict__ logs,
    int*   __restrict__ cnt,
    float* __restrict__ out)
{
    __shared__ __align__(16) float sP[4][NT][NY];   // 36 KB
    __shared__ __align__(16) float sI[4][NT][NY];   // 36 KB
    __shared__ int   sT[4][NT];
    __shared__ int   sLast;
    __shared__ float sRed[4];

    const int tid = threadIdx.x;
    const int b0  = blockIdx.x * 4;

    if (tid == 0) sLast = 0;
    if (tid < 4 * NT) ((int*)sT)[tid] = tgt[b0 * NT + tid];

    // Stage 4 b's of compacted gather data (2*36 KB) via float4, coalesced.
    const float4* p4 = (const float4*)(wsP + (size_t)b0 * EPB);
    const float4* i4 = (const float4*)(wsI + (size_t)b0 * EPB);
    float4* sp4 = (float4*)&sP[0][0][0];
    float4* si4 = (float4*)&sI[0][0][0];
    #pragma unroll
    for (int k = 0; k < 9; ++k) {
        sp4[tid + k * 256] = p4[tid + k * 256];
        si4[tid + k * 256] = i4[tid + k * 256];
    }
    __syncthreads();

    const int w = tid >> 6;          // wave -> batch b0+w
    const int j = tid & 63;
    const int b = b0 + w;

    if (j < NY) {
        const float* Rb = R + ((size_t)b * NY + j) * 3;
        float R0 = Rb[0];
        float R1 = Rb[1];
        float R2 = Rb[2];
        float Imult  = (j == NY - 1) ? 1.0f : R1;
        float R2prev = dpp_movf<0x138, 0xf>(0.0f, R2);

        // row0: multiplicative scan of d0
        float d0 = (sT[w][0] == 1) ? 1.0f : R2;
        float v  = (j == 0) ? 1.0f : d0;
        v *= dpp_movf<0x111, 0xf>(1.0f, v);
        v *= dpp_movf<0x112, 0xf>(1.0f, v);
        v *= dpp_movf<0x114, 0xf>(1.0f, v);
        v *= dpp_movf<0x118, 0xf>(1.0f, v);
        v *= dpp_movf<0x142, 0xa>(1.0f, v);
        v *= dpp_movf<0x143, 0xc>(1.0f, v);
        float row = v;

        float pg = sP[w][0][j];
        float ig = sI[w][0][j];
        for (int t = 0; t < NT - 1; ++t) {
            float pgn = sP[w][t + 1][j];     // prefetch next iteration
            float ign = sI[w][t + 1][j];

            float u  = row * (R0 * pg);
            float up = dpp_movf<0x138, 0xf>(0.0f, u);
            float c  = fmaf(row, Imult * ig, up);
            float m  = (j == 0) ? 0.0f : ((sT[w][t + 1] == 1) ? 1.0f : R2prev);

            { float mp = dpp_movf<0x111, 0xf>(1.0f, m), cp = dpp_movf<0x111, 0xf>(0.0f, c); c = fmaf(m, cp, c); m *= mp; }
            { float mp = dpp_movf<0x112, 0xf>(1.0f, m), cp = dpp_movf<0x112, 0xf>(0.0f, c); c = fmaf(m, cp, c); m *= mp; }
            { float mp = dpp_movf<0x114, 0xf>(1.0f, m), cp = dpp_movf<0x114, 0xf>(0.0f, c); c = fmaf(m, cp, c); m *= mp; }
            { float mp = dpp_movf<0x118, 0xf>(1.0f, m), cp = dpp_movf<0x118, 0xf>(0.0f, c); c = fmaf(m, cp, c); m *= mp; }
            { float mp = dpp_movf<0x142, 0xa>(1.0f, m), cp = dpp_movf<0x142, 0xa>(0.0f, c); c = fmaf(m, cp, c); m *= mp; }
            { float mp = dpp_movf<0x143, 0xc>(1.0f, m), cp = dpp_movf<0x143, 0xc>(0.0f, c); c = fmaf(m, cp, c); m *= mp; }
            row = c;

            pg = pgn; ig = ign;
        }

        if (j == NY - 1) {
            logs[b] = logf(row);
            __threadfence();                 // release this wave's log
            int old = __hip_atomic_fetch_add(cnt, 1, __ATOMIC_ACQ_REL,
                                             __HIP_MEMORY_SCOPE_AGENT);
            if (old == B_ - 1) sLast = 1;    // 192 waves total
        }
    }
    __syncthreads();

    // Last-finishing block: deterministic fixed-order reduction of 192 logs.
    if (sLast) {
        float x = 0.0f;
        if (tid < B_)
            x = __hip_atomic_load(&logs[tid], __ATOMIC_RELAXED,
                                  __HIP_MEMORY_SCOPE_AGENT);
        #pragma unroll
        for (int s = 1; s < 64; s <<= 1) x += __shfl_xor(x, s);
        if ((tid & 63) == 0 && tid < B_) sRed[tid >> 6] = x;
        __syncthreads();
        if (tid == 0) out[0] = (sRed[0] + sRed[1] + sRed[2]) * (1.0f / (float)B_);
    }
}

extern "C" void kernel_launch(void* const* d_in, const int* in_sizes, int n_in,
                              void* d_out, int out_size, void* d_ws, size_t ws_size,
                              hipStream_t stream) {
    const float* pred = (const float*)d_in[0];
    const float* R    = (const float*)d_in[1];
    const float* I    = (const float*)d_in[2];
    const int*   tgt  = (const int*)d_in[3];
    float* out  = (float*)d_out;

    char* ws = (char*)d_ws;
    float* wsP  = (float*)(ws);                              // 442368 floats
    float* wsI  = (float*)(ws + 1769472);                    // 442368 floats
    float* logs = (float*)(ws + 3538944);                    // 192 floats
    int*   cnt  = (int*)  (ws + 3539712);                    // 1 int

    ep_gather_kernel<<<(B_ * EPB) / 256, 256, 0, stream>>>(pred, I, tgt, wsP, wsI, cnt);
    ep_scan_kernel<<<B_ / 4, 256, 0, stream>>>(R, tgt, wsP, wsI, logs, cnt, out);
}

// Round 4
// 34.796 us; speedup vs baseline: 1.1372x; 1.1372x over previous
//
#include <hip/hip_runtime.h>
#include <hip/hip_bf16.h>
#include <math.h>

// Problem constants (from reference setup_inputs)
constexpr int B_  = 192;
constexpr int NY  = 48;
constexpr int NT  = 48;
constexpr int C_  = 6625;

// Kernel 1: one block per batch element b.
// Phase 1 (256 threads): gather relu'd pred/I values for all (t,j) into LDS,
//   with t-INNER lane ordering: consecutive lanes take consecutive t at fixed j,
//   so one wave's 64 scattered accesses land inside ~two 26.5 KB windows
//   (48 random columns of ONE pred row) -> DRAM row-buffer locality.
// Phase 2 (wave 0, lanes 0..47): affine-scan recurrence over t; lane j = state j.
__global__ __launch_bounds__(256) void ep_forward_kernel(
    const float* __restrict__ pred,
    const float* __restrict__ R,
    const float* __restrict__ I,
    const int*   __restrict__ tgt,
    float* __restrict__ out_logs)
{
    __shared__ float sP[NT][NY + 1];   // +1 pad: t-inner writes -> stride 49
    __shared__ float sI[NT][NY + 1];   //   bank(t)=17t+j mod 32, only 2-way alias
    __shared__ int   sT[NT];

    const int b   = blockIdx.x;
    const int tid = threadIdx.x;

    if (tid < NT) sT[tid] = tgt[b * NT + tid];
    __syncthreads();

    // ---- Phase 1: gather (2304 elements per array, 9 per thread) ----
    const float* predB = pred + (size_t)b * NY * C_;
    const float* IB    = I    + (size_t)b * NY * C_;
    #pragma unroll
    for (int k = 0; k < 9; ++k) {
        int e = tid + k * 256;           // e in [0, 2304)
        int j = e / NT;                  // t-inner: lane-consecutive e -> consecutive t
        int t = e - j * NT;
        int c = sT[t];
        size_t off = (size_t)j * C_ + (size_t)c;
        sP[t][j] = fmaxf(predB[off], 0.0f);
        sI[t][j] = fmaxf(IB[off],    0.0f);
    }
    __syncthreads();

    // ---- Phase 2: recurrence (wave 0, lanes 0..47 only) ----
    if (tid >= NY) return;
    const int j = tid;

    const float* Rb = R + ((size_t)b * NY + j) * 3;
    float R0 = Rb[0];
    float R1 = Rb[1];
    float R2 = Rb[2];
    float Imult  = (j == NY - 1) ? 1.0f : R1;
    float R2prev = __shfl_up(R2, 1);     // R2[j-1]; lane 0 value is masked below

    // row0[j] = prod_{k=1..j} pD[b,0,k],  pD[b,0,k] = (tgt[0]==1) ? 1 : R2[k]
    {
        float d0 = (sT[0] == 1) ? 1.0f : R2;
        float v  = (j == 0) ? 1.0f : d0;
        #pragma unroll
        for (int s = 1; s < 64; s <<= 1) {
            float p = __shfl_up(v, s);
            if (j >= s) v *= p;
        }
        float row = v;

        for (int t = 0; t < NT - 1; ++t) {
            float pg = sP[t][j];
            float ig = sI[t][j];
            float pC = R0 * pg;
            float pI = Imult * ig;

            // a[j] = row[j]*pI[j] + row[j-1]*pC[j-1]
            float u  = row * pC;
            float up = __shfl_up(u, 1);
            float a  = row * pI + ((j >= 1) ? up : 0.0f);

            // x_j = a_j + x_{j-1} * d_{j-1},  d = pD[b,t+1,*]
            bool is1 = (sT[t + 1] == 1);
            float m = (j == 0) ? 0.0f : (is1 ? 1.0f : R2prev);
            float c = a;
            // Hillis-Steele scan of affine maps f_j(x) = m_j x + c_j
            #pragma unroll
            for (int s = 1; s < 64; s <<= 1) {
                float cp = __shfl_up(c, s);
                float mp = __shfl_up(m, s);
                if (j >= s) {
                    c = fmaf(m, cp, c);  // uses OLD m
                    m = m * mp;
                }
            }
            row = c;
        }

        if (j == NY - 1) out_logs[b] = logf(row);
    }
}

// Kernel 2: deterministic reduction of 192 per-batch logs -> mean
__global__ __launch_bounds__(256) void ep_reduce_kernel(
    const float* __restrict__ logs, float* __restrict__ out)
{
    const int tid = threadIdx.x;
    float v = (tid < B_) ? logs[tid] : 0.0f;
    #pragma unroll
    for (int s = 1; s < 64; s <<= 1) v += __shfl_xor(v, s);
    __shared__ float sw[4];
    if ((tid & 63) == 0) sw[tid >> 6] = v;
    __syncthreads();
    if (tid == 0) out[0] = (sw[0] + sw[1] + sw[2] + sw[3]) * (1.0f / (float)B_);
}

extern "C" void kernel_launch(void* const* d_in, const int* in_sizes, int n_in,
                              void* d_out, int out_size, void* d_ws, size_t ws_size,
                              hipStream_t stream) {
    const float* pred = (const float*)d_in[0];
    const float* R    = (const float*)d_in[1];
    const float* I    = (const float*)d_in[2];
    const int*   tgt  = (const int*)d_in[3];
    float* out  = (float*)d_out;
    float* logs = (float*)d_ws;   // 192 floats of scratch

    ep_forward_kernel<<<B_, 256, 0, stream>>>(pred, R, I, tgt, logs);
    ep_reduce_kernel<<<1, 256, 0, stream>>>(logs, out);
}